// Round 1
// baseline (2530.926 us; speedup 1.0000x reference)
//
#include <hip/hip_runtime.h>
#include <cmath>

// ---------------------------------------------------------------------------
// conv1x1: out[b,oc,n] = bias[oc] + sum_c w[oc,c] * x[b,c,n]
// grid (ceil(N/64), ceil(OC/64), B), block 256, 64x64 tile, 4x4 per thread
// ---------------------------------------------------------------------------
__global__ __launch_bounds__(256) void conv1x1_kernel(
    const float* __restrict__ x, const float* __restrict__ w,
    const float* __restrict__ bias, float* __restrict__ out,
    int C, int N, int OC) {
  __shared__ float As[64][17];   // [m][k] weights (coalesced stage)
  __shared__ float Bs[16][64];   // [k][n] x
  const int b = blockIdx.z;
  const int m0 = blockIdx.y * 64, n0 = blockIdx.x * 64;
  const float* xb = x + (size_t)b * C * N;
  const int tid = threadIdx.x;
  const int tr = tid >> 4, tc = tid & 15;
  float acc[4][4] = {};
  for (int k0 = 0; k0 < C; k0 += 16) {
    for (int i = tid; i < 64 * 16; i += 256) {
      int m = i >> 4, kk = i & 15;
      int gm = m0 + m;
      As[m][kk] = (gm < OC) ? w[(size_t)gm * C + k0 + kk] : 0.f;
    }
    for (int i = tid; i < 16 * 64; i += 256) {
      int kk = i >> 6, n = i & 63;
      int gn = n0 + n;
      Bs[kk][n] = (gn < N) ? xb[(size_t)(k0 + kk) * N + gn] : 0.f;
    }
    __syncthreads();
#pragma unroll
    for (int kk = 0; kk < 16; ++kk) {
      float a[4], bb[4];
#pragma unroll
      for (int i = 0; i < 4; i++) a[i] = As[tr * 4 + i][kk];
#pragma unroll
      for (int j = 0; j < 4; j++) bb[j] = Bs[kk][tc * 4 + j];
#pragma unroll
      for (int i = 0; i < 4; i++)
#pragma unroll
        for (int j = 0; j < 4; j++) acc[i][j] += a[i] * bb[j];
    }
    __syncthreads();
  }
  for (int i = 0; i < 4; i++) {
    int gm = m0 + tr * 4 + i;
    if (gm >= OC) continue;
    float bv = bias[gm];
    for (int j = 0; j < 4; j++) {
      int gn = n0 + tc * 4 + j;
      if (gn < N) out[((size_t)b * OC + gm) * N + gn] = acc[i][j] + bv;
    }
  }
}

// ---------------------------------------------------------------------------
// energy[b,n,m] = sum_q q[b,q,n] * k[b,q,m]    (K = QKd = 32)
// grid (ceil(N/64) [m], ceil(N/64) [n], B)
// ---------------------------------------------------------------------------
__global__ __launch_bounds__(256) void energy_kernel(
    const float* __restrict__ qg, const float* __restrict__ kg,
    float* __restrict__ e, int QKd, int N) {
  __shared__ float As[16][64];  // [kq][n]
  __shared__ float Bs[16][64];  // [kq][m]
  const int b = blockIdx.z;
  const int n0 = blockIdx.y * 64, m0 = blockIdx.x * 64;
  const float* qb = qg + (size_t)b * QKd * N;
  const float* kb = kg + (size_t)b * QKd * N;
  const int tid = threadIdx.x, tr = tid >> 4, tc = tid & 15;
  float acc[4][4] = {};
  for (int k0 = 0; k0 < QKd; k0 += 16) {
    for (int i = tid; i < 16 * 64; i += 256) {
      int kk = i >> 6, n = i & 63;
      int gn = n0 + n;
      As[kk][n] = (gn < N) ? qb[(size_t)(k0 + kk) * N + gn] : 0.f;
    }
    for (int i = tid; i < 16 * 64; i += 256) {
      int kk = i >> 6, m = i & 63;
      int gm = m0 + m;
      Bs[kk][m] = (gm < N) ? kb[(size_t)(k0 + kk) * N + gm] : 0.f;
    }
    __syncthreads();
#pragma unroll
    for (int kk = 0; kk < 16; ++kk) {
      float a[4], bb[4];
#pragma unroll
      for (int i = 0; i < 4; i++) a[i] = As[kk][tr * 4 + i];
#pragma unroll
      for (int j = 0; j < 4; j++) bb[j] = Bs[kk][tc * 4 + j];
#pragma unroll
      for (int i = 0; i < 4; i++)
#pragma unroll
        for (int j = 0; j < 4; j++) acc[i][j] += a[i] * bb[j];
    }
    __syncthreads();
  }
  for (int i = 0; i < 4; i++) {
    int gn = n0 + tr * 4 + i;
    if (gn >= N) continue;
    for (int j = 0; j < 4; j++) {
      int gm = m0 + tc * 4 + j;
      if (gm < N) e[((size_t)b * N + gn) * N + gm] = acc[i][j];
    }
  }
}

// ---------------------------------------------------------------------------
// in-place row softmax of sign*r over last dim. grid = (#rows), block 256.
// ---------------------------------------------------------------------------
__global__ __launch_bounds__(256) void softmax_rows_kernel(
    float* __restrict__ e, int N, float sign) {
  const size_t row = blockIdx.x;
  float* r = e + row * (size_t)N;
  const int tid = threadIdx.x;
  __shared__ float red[4];
  float mx = -1e30f;
  for (int i = tid; i < N; i += 256) mx = fmaxf(mx, sign * r[i]);
#pragma unroll
  for (int off = 32; off; off >>= 1) mx = fmaxf(mx, __shfl_xor(mx, off, 64));
  if ((tid & 63) == 0) red[tid >> 6] = mx;
  __syncthreads();
  if (tid == 0) {
    float m2 = red[0];
    for (int i = 1; i < 4; i++) m2 = fmaxf(m2, red[i]);
    red[0] = m2;
  }
  __syncthreads();
  mx = red[0];
  __syncthreads();
  float s = 0.f;
  for (int i = tid; i < N; i += 256) {
    float v = __expf(sign * r[i] - mx);
    r[i] = v;
    s += v;
  }
#pragma unroll
  for (int off = 32; off; off >>= 1) s += __shfl_xor(s, off, 64);
  if ((tid & 63) == 0) red[tid >> 6] = s;
  __syncthreads();
  if (tid == 0) {
    float t = 0.f;
    for (int i = 0; i < 4; i++) t += red[i];
    red[0] = t;
  }
  __syncthreads();
  const float inv = 1.f / red[0];
  for (int i = tid; i < N; i += 256) r[i] *= inv;
}

// ---------------------------------------------------------------------------
// xsum[b,c,n] = x[b,c,n] + g * sum_m v[b,c,m] * A[b,n,m]
// grid (ceil(N/64) [n], C/64 [c], B)
// ---------------------------------------------------------------------------
__global__ __launch_bounds__(256) void pv_add_kernel(
    const float* __restrict__ v, const float* __restrict__ A,
    const float* __restrict__ x, const float* __restrict__ gp,
    float* __restrict__ xsum, int C, int N) {
  __shared__ float Vs[64][17];  // [c][k]
  __shared__ float At[64][17];  // [n][k]
  const int b = blockIdx.z;
  const int c0 = blockIdx.y * 64, n0 = blockIdx.x * 64;
  const float* vb = v + (size_t)b * C * N;
  const float* Ab = A + (size_t)b * N * N;
  const int tid = threadIdx.x, tr = tid >> 4, tc = tid & 15;
  float acc[4][4] = {};
  for (int k0 = 0; k0 < N; k0 += 16) {
    for (int i = tid; i < 64 * 16; i += 256) {
      int rr = i >> 4, kk = i & 15;
      int gk = k0 + kk;
      Vs[rr][kk] = (gk < N) ? vb[(size_t)(c0 + rr) * N + gk] : 0.f;
    }
    for (int i = tid; i < 64 * 16; i += 256) {
      int rr = i >> 4, kk = i & 15;
      int gn = n0 + rr, gk = k0 + kk;
      At[rr][kk] = (gn < N && gk < N) ? Ab[(size_t)gn * N + gk] : 0.f;
    }
    __syncthreads();
#pragma unroll
    for (int kk = 0; kk < 16; ++kk) {
      float a[4], bb[4];
#pragma unroll
      for (int i = 0; i < 4; i++) a[i] = Vs[tr * 4 + i][kk];
#pragma unroll
      for (int j = 0; j < 4; j++) bb[j] = At[tc * 4 + j][kk];
#pragma unroll
      for (int i = 0; i < 4; i++)
#pragma unroll
        for (int j = 0; j < 4; j++) acc[i][j] += a[i] * bb[j];
    }
    __syncthreads();
  }
  const float g = *gp;
  for (int i = 0; i < 4; i++) {
    int gc = c0 + tr * 4 + i;
    for (int j = 0; j < 4; j++) {
      int gn = n0 + tc * 4 + j;
      if (gn < N) {
        size_t idx = ((size_t)b * C + gc) * N + gn;
        xsum[idx] = x[idx] + g * acc[i][j];
      }
    }
  }
}

// ---------------------------------------------------------------------------
// gram: e[b,c,d] = sum_n x[b,c,n] * x[b,d,n]
// grid (C/64 [d], C/64 [c], B)
// ---------------------------------------------------------------------------
__global__ __launch_bounds__(256) void gram_kernel(
    const float* __restrict__ x, float* __restrict__ e, int C, int N) {
  __shared__ float Xs[64][17];
  __shared__ float Ys[64][17];
  const int b = blockIdx.z;
  const int c0 = blockIdx.y * 64, d0 = blockIdx.x * 64;
  const float* xb = x + (size_t)b * C * N;
  const int tid = threadIdx.x, tr = tid >> 4, tc = tid & 15;
  float acc[4][4] = {};
  for (int k0 = 0; k0 < N; k0 += 16) {
    for (int i = tid; i < 1024; i += 256) {
      int rr = i >> 4, kk = i & 15;
      int gk = k0 + kk;
      Xs[rr][kk] = (gk < N) ? xb[(size_t)(c0 + rr) * N + gk] : 0.f;
    }
    for (int i = tid; i < 1024; i += 256) {
      int rr = i >> 4, kk = i & 15;
      int gk = k0 + kk;
      Ys[rr][kk] = (gk < N) ? xb[(size_t)(d0 + rr) * N + gk] : 0.f;
    }
    __syncthreads();
#pragma unroll
    for (int kk = 0; kk < 16; ++kk) {
      float a[4], bb[4];
#pragma unroll
      for (int i = 0; i < 4; i++) a[i] = Xs[tr * 4 + i][kk];
#pragma unroll
      for (int j = 0; j < 4; j++) bb[j] = Ys[tc * 4 + j][kk];
#pragma unroll
      for (int i = 0; i < 4; i++)
#pragma unroll
        for (int j = 0; j < 4; j++) acc[i][j] += a[i] * bb[j];
    }
    __syncthreads();
  }
  for (int i = 0; i < 4; i++)
    for (int j = 0; j < 4; j++)
      e[((size_t)b * C + c0 + tr * 4 + i) * C + d0 + tc * 4 + j] = acc[i][j];
}

// ---------------------------------------------------------------------------
// xsum[b,c,n] += sum_d (w1*Aown[b,c,d] + w2*Aoth[b,c,d]) * x[b,d,n]
// grid (ceil(N/64) [n], C/64 [c], B)
// ---------------------------------------------------------------------------
__global__ __launch_bounds__(256) void chan_use_kernel(
    const float* __restrict__ Aown, const float* __restrict__ Aoth,
    const float* __restrict__ w1p, const float* __restrict__ w2p,
    const float* __restrict__ x, float* __restrict__ xsum, int C, int N) {
  __shared__ float Ms[64][17];  // [c][k=d]
  __shared__ float Bs[16][64];  // [k=d][n]
  const int b = blockIdx.z;
  const int c0 = blockIdx.y * 64, n0 = blockIdx.x * 64;
  const float w1 = *w1p, w2 = *w2p;
  const float* Ao = Aown + (size_t)b * C * C;
  const float* Ax = Aoth + (size_t)b * C * C;
  const float* xb = x + (size_t)b * C * N;
  const int tid = threadIdx.x, tr = tid >> 4, tc = tid & 15;
  float acc[4][4] = {};
  for (int k0 = 0; k0 < C; k0 += 16) {
    for (int i = tid; i < 1024; i += 256) {
      int rr = i >> 4, kk = i & 15;
      size_t ii = (size_t)(c0 + rr) * C + k0 + kk;
      Ms[rr][kk] = w1 * Ao[ii] + w2 * Ax[ii];
    }
    for (int i = tid; i < 1024; i += 256) {
      int kk = i >> 6, n = i & 63;
      int gn = n0 + n;
      Bs[kk][n] = (gn < N) ? xb[(size_t)(k0 + kk) * N + gn] : 0.f;
    }
    __syncthreads();
#pragma unroll
    for (int kk = 0; kk < 16; ++kk) {
      float a[4], bb[4];
#pragma unroll
      for (int i = 0; i < 4; i++) a[i] = Ms[tr * 4 + i][kk];
#pragma unroll
      for (int j = 0; j < 4; j++) bb[j] = Bs[kk][tc * 4 + j];
#pragma unroll
      for (int i = 0; i < 4; i++)
#pragma unroll
        for (int j = 0; j < 4; j++) acc[i][j] += a[i] * bb[j];
    }
    __syncthreads();
  }
  for (int i = 0; i < 4; i++) {
    int gc = c0 + tr * 4 + i;
    for (int j = 0; j < 4; j++) {
      int gn = n0 + tc * 4 + j;
      if (gn < N) xsum[((size_t)b * C + gc) * N + gn] += acc[i][j];
    }
  }
}

// ---------------------------------------------------------------------------
// 3x3 offset conv (27 out channels, pad 1): om[b,o,p]
// grid (ceil(27*N/256), B)
// ---------------------------------------------------------------------------
__global__ __launch_bounds__(256) void offconv_kernel(
    const float* __restrict__ xsum, const float* __restrict__ ow,
    const float* __restrict__ ob, float* __restrict__ om,
    int C, int H, int Wd) {
  const int N = H * Wd;
  const int b = blockIdx.y;
  const int flat = blockIdx.x * 256 + threadIdx.x;
  if (flat >= 27 * N) return;
  const int o = flat / N, p = flat % N;
  const int h = p / Wd, w = p % Wd;
  const float* xb = xsum + (size_t)b * C * N;
  float acc = ob[o];
  for (int c = 0; c < C; c++) {
    const float* xc = xb + (size_t)c * N;
    const float* wc = ow + ((size_t)o * C + c) * 9;
#pragma unroll
    for (int ky = 0; ky < 3; ky++) {
      int yy = h + ky - 1;
      if (yy < 0 || yy >= H) continue;
#pragma unroll
      for (int kx = 0; kx < 3; kx++) {
        int xx = w + kx - 1;
        if (xx < 0 || xx >= Wd) continue;
        acc += xc[yy * Wd + xx] * wc[ky * 3 + kx];
      }
    }
  }
  om[((size_t)b * 27 + o) * N + p] = acc;
}

// ---------------------------------------------------------------------------
// transpose DCN weights (O,C,3,3) -> Wt[k][c][o]
// ---------------------------------------------------------------------------
__global__ __launch_bounds__(256) void transposeW_kernel(
    const float* __restrict__ W, float* __restrict__ Wt, int C) {
  const int i = blockIdx.x * 256 + threadIdx.x;
  if (i >= C * C * 9) return;
  const int k = i % 9;
  const int c = (i / 9) % C;
  const int o = i / (9 * C);
  Wt[((size_t)k * C + c) * C + o] = W[i];
}

// ---------------------------------------------------------------------------
// modulated deformable conv, fused bilinear gather + implicit GEMM
// grid (ceil(N/32), B), block 256; thread handles 4 o x 8 p
// ---------------------------------------------------------------------------
__global__ __launch_bounds__(256) void dcn_kernel(
    const float* __restrict__ xsum, const float* __restrict__ om,
    const float* __restrict__ Wt, const float* __restrict__ bias,
    float* __restrict__ out, int C, int H, int Wd) {
  const int N = H * Wd;
  const int b = blockIdx.y;
  const int p0 = blockIdx.x * 32;
  __shared__ float vals[256][32];
  __shared__ int sidx[4][32];
  __shared__ float swt[4][32];
  const int tid = threadIdx.x;
  const int og = tid >> 2;  // 0..63 -> o = og*4+i
  const int pg = tid & 3;   // 0..3  -> p = pg*8+j
  float acc[4][8];
#pragma unroll
  for (int i = 0; i < 4; i++)
#pragma unroll
    for (int j = 0; j < 8; j++) acc[i][j] = 0.f;
  const float* xb = xsum + (size_t)b * C * N;

  for (int k = 0; k < 9; k++) {
    __syncthreads();  // previous iteration's consumers done
    if (tid < 32) {
      const int p = p0 + tid;
      float wts[4];
      int idxs[4];
      if (p < N) {
        const int ky = k / 3, kx = k % 3;
        const int h = p / Wd, w = p % Wd;
        const float* omb = om + (size_t)b * 27 * N;
        const float offy = omb[(size_t)k * N + p];
        const float offx = omb[(size_t)(9 + k) * N + p];
        const float mraw = omb[(size_t)(18 + k) * N + p];
        const float mval = 1.f / (1.f + __expf(-mraw));
        const float py = offy + (float)h + (float)(ky - 1);
        const float px = offx + (float)w + (float)(kx - 1);
        const float y0f = floorf(py), x0f = floorf(px);
        const float wy = py - y0f, wx = px - x0f;
        const int y0 = (int)y0f, x0 = (int)x0f;
        const int ys[2] = {y0, y0 + 1};
        const int xs2[2] = {x0, x0 + 1};
        const float wyv[2] = {1.f - wy, wy};
        const float wxv[2] = {1.f - wx, wx};
#pragma unroll
        for (int a = 0; a < 2; a++)
#pragma unroll
          for (int bb = 0; bb < 2; bb++) {
            const int yi = ys[a], xi = xs2[bb];
            const bool valid = (yi >= 0) && (yi < H) && (xi >= 0) && (xi < Wd);
            const int yc = min(max(yi, 0), H - 1);
            const int xc = min(max(xi, 0), Wd - 1);
            idxs[a * 2 + bb] = yc * Wd + xc;
            wts[a * 2 + bb] = valid ? wyv[a] * wxv[bb] * mval : 0.f;
          }
      } else {
#pragma unroll
        for (int q = 0; q < 4; q++) {
          idxs[q] = 0;
          wts[q] = 0.f;
        }
      }
#pragma unroll
      for (int q = 0; q < 4; q++) {
        sidx[q][tid] = idxs[q];
        swt[q][tid] = wts[q];
      }
    }
    __syncthreads();
    {
      const int c0 = tid >> 5;  // 0..7
      const int p = tid & 31;
      const int i0 = sidx[0][p], i1 = sidx[1][p], i2 = sidx[2][p], i3 = sidx[3][p];
      const float w0 = swt[0][p], w1 = swt[1][p], w2 = swt[2][p], w3 = swt[3][p];
      for (int cc = c0; cc < 256; cc += 8) {
        const float* xc = xb + (size_t)cc * N;
        vals[cc][p] = w0 * xc[i0] + w1 * xc[i1] + w2 * xc[i2] + w3 * xc[i3];
      }
    }
    __syncthreads();
    const float* wkbase = Wt + (size_t)k * C * C;
    for (int c = 0; c < 256; c++) {
      const float4 wv = *reinterpret_cast<const float4*>(wkbase + (size_t)c * C + og * 4);
      const float4 v0 = *reinterpret_cast<const float4*>(&vals[c][pg * 8]);
      const float4 v1 = *reinterpret_cast<const float4*>(&vals[c][pg * 8 + 4]);
      const float wa[4] = {wv.x, wv.y, wv.z, wv.w};
      const float vb2[8] = {v0.x, v0.y, v0.z, v0.w, v1.x, v1.y, v1.z, v1.w};
#pragma unroll
      for (int i = 0; i < 4; i++)
#pragma unroll
        for (int j = 0; j < 8; j++) acc[i][j] += wa[i] * vb2[j];
    }
  }
#pragma unroll
  for (int i = 0; i < 4; i++) {
    const int o = og * 4 + i;
    const float bv = bias[o];
#pragma unroll
    for (int j = 0; j < 8; j++) {
      const int gp = p0 + pg * 8 + j;
      if (gp < N) out[((size_t)b * C + o) * N + gp] = acc[i][j] + bv;
    }
  }
}

// ---------------------------------------------------------------------------
extern "C" void kernel_launch(void* const* d_in, const int* in_sizes, int n_in,
                              void* d_out, int out_size, void* d_ws, size_t ws_size,
                              hipStream_t stream) {
  const float* t_in = (const float*)d_in[0];
  const float* s_in = (const float*)d_in[1];
  const float* t_qw = (const float*)d_in[2];
  const float* t_qb = (const float*)d_in[3];
  const float* t_kw = (const float*)d_in[4];
  const float* t_kb = (const float*)d_in[5];
  const float* t_vw = (const float*)d_in[6];
  const float* t_vb = (const float*)d_in[7];
  const float* t_g = (const float*)d_in[8];
  const float* s_qw = (const float*)d_in[9];
  const float* s_qb = (const float*)d_in[10];
  const float* s_kw = (const float*)d_in[11];
  const float* s_kb = (const float*)d_in[12];
  const float* s_vw = (const float*)d_in[13];
  const float* s_vb = (const float*)d_in[14];
  const float* s_g = (const float*)d_in[15];
  const float* w_t_ch = (const float*)d_in[16];
  const float* w_s_ch = (const float*)d_in[17];
  const float* w_s2t = (const float*)d_in[18];
  const float* w_t2s = (const float*)d_in[19];
  const float* t_off_w = (const float*)d_in[20];
  const float* t_off_b = (const float*)d_in[21];
  const float* t_dcn_w = (const float*)d_in[22];
  const float* t_dcn_b = (const float*)d_in[23];
  const float* s_off_w = (const float*)d_in[24];
  const float* s_off_b = (const float*)d_in[25];
  const float* s_dcn_w = (const float*)d_in[26];
  const float* s_dcn_b = (const float*)d_in[27];
  (void)in_sizes; (void)n_in; (void)out_size; (void)ws_size;

  constexpr int Bn = 16, C = 256, QKd = 32;
  constexpr int HT = 15, WT = 15, NT = HT * WT;    // 225
  constexpr int HS = 31, WS2 = 31, NS = HS * WS2;  // 961

  float* ws = (float*)d_ws;
  size_t off = 0;
  auto alloc = [&](size_t n) { float* p = ws + off; off += n; return p; };
  float* q_t = alloc((size_t)Bn * QKd * NT);
  float* k_t = alloc((size_t)Bn * QKd * NT);
  float* v_t = alloc((size_t)Bn * C * NT);
  float* q_s = alloc((size_t)Bn * QKd * NS);
  float* k_s = alloc((size_t)Bn * QKd * NS);
  float* v_s = alloc((size_t)Bn * C * NS);
  float* At = alloc((size_t)Bn * NT * NT);
  float* As = alloc((size_t)Bn * NS * NS);
  float* xt = alloc((size_t)Bn * C * NT);
  float* xs = alloc((size_t)Bn * C * NS);
  float* Atc = alloc((size_t)Bn * C * C);
  float* Asc = alloc((size_t)Bn * C * C);
  float* om_t = alloc((size_t)Bn * 27 * NT);
  float* om_s = alloc((size_t)Bn * 27 * NS);
  float* Wt_t = alloc((size_t)9 * C * C);
  float* Wt_s = alloc((size_t)9 * C * C);

  dim3 blk(256);

  // q, k, v (conv1x1)
  conv1x1_kernel<<<dim3(4, 1, Bn), blk, 0, stream>>>(t_in, t_qw, t_qb, q_t, C, NT, QKd);
  conv1x1_kernel<<<dim3(4, 1, Bn), blk, 0, stream>>>(t_in, t_kw, t_kb, k_t, C, NT, QKd);
  conv1x1_kernel<<<dim3(4, 4, Bn), blk, 0, stream>>>(t_in, t_vw, t_vb, v_t, C, NT, C);
  conv1x1_kernel<<<dim3(16, 1, Bn), blk, 0, stream>>>(s_in, s_qw, s_qb, q_s, C, NS, QKd);
  conv1x1_kernel<<<dim3(16, 1, Bn), blk, 0, stream>>>(s_in, s_kw, s_kb, k_s, C, NS, QKd);
  conv1x1_kernel<<<dim3(16, 4, Bn), blk, 0, stream>>>(s_in, s_vw, s_vb, v_s, C, NS, C);

  // spatial attention
  energy_kernel<<<dim3(4, 4, Bn), blk, 0, stream>>>(q_t, k_t, At, QKd, NT);
  energy_kernel<<<dim3(16, 16, Bn), blk, 0, stream>>>(q_s, k_s, As, QKd, NS);
  softmax_rows_kernel<<<dim3(Bn * NT), blk, 0, stream>>>(At, NT, 1.f);
  softmax_rows_kernel<<<dim3(Bn * NS), blk, 0, stream>>>(As, NS, 1.f);
  pv_add_kernel<<<dim3(4, 4, Bn), blk, 0, stream>>>(v_t, At, t_in, t_g, xt, C, NT);
  pv_add_kernel<<<dim3(16, 4, Bn), blk, 0, stream>>>(v_s, As, s_in, s_g, xs, C, NS);

  // channel attention (A = softmax(-gram))
  gram_kernel<<<dim3(4, 4, Bn), blk, 0, stream>>>(t_in, Atc, C, NT);
  gram_kernel<<<dim3(4, 4, Bn), blk, 0, stream>>>(s_in, Asc, C, NS);
  softmax_rows_kernel<<<dim3(Bn * C), blk, 0, stream>>>(Atc, C, -1.f);
  softmax_rows_kernel<<<dim3(Bn * C), blk, 0, stream>>>(Asc, C, -1.f);
  // xsum += (w1*Aown + w2*Aoth) @ x   (fuses ch + cross terms)
  chan_use_kernel<<<dim3(4, 4, Bn), blk, 0, stream>>>(Atc, Asc, w_t_ch, w_s2t, t_in, xt, C, NT);
  chan_use_kernel<<<dim3(16, 4, Bn), blk, 0, stream>>>(Asc, Atc, w_s_ch, w_t2s, s_in, xs, C, NS);

  // offsets
  offconv_kernel<<<dim3((27 * NT + 255) / 256, Bn), blk, 0, stream>>>(xt, t_off_w, t_off_b, om_t, C, HT, WT);
  offconv_kernel<<<dim3((27 * NS + 255) / 256, Bn), blk, 0, stream>>>(xs, s_off_w, s_off_b, om_s, C, HS, WS2);

  // DCN
  transposeW_kernel<<<dim3((C * C * 9 + 255) / 256), blk, 0, stream>>>(t_dcn_w, Wt_t, C);
  transposeW_kernel<<<dim3((C * C * 9 + 255) / 256), blk, 0, stream>>>(s_dcn_w, Wt_s, C);

  float* out_t = (float*)d_out;
  float* out_s = out_t + (size_t)Bn * C * NT;
  dcn_kernel<<<dim3((NT + 31) / 32, Bn), blk, 0, stream>>>(xt, om_t, Wt_t, t_dcn_b, out_t, C, HT, WT);
  dcn_kernel<<<dim3((NS + 31) / 32, Bn), blk, 0, stream>>>(xs, om_s, Wt_s, s_dcn_b, out_s, C, HS, WS2);
}

// Round 2
// 1688.338 us; speedup vs baseline: 1.4991x; 1.4991x over previous
//
#include <hip/hip_runtime.h>
#include <cmath>

// ---------------------------------------------------------------------------
// conv1x1: out[b,oc,n] = bias[oc] + sum_c w[oc,c] * x[b,c,n]
// ---------------------------------------------------------------------------
__global__ __launch_bounds__(256) void conv1x1_kernel(
    const float* __restrict__ x, const float* __restrict__ w,
    const float* __restrict__ bias, float* __restrict__ out,
    int C, int N, int OC) {
  __shared__ float As[64][17];
  __shared__ float Bs[16][64];
  const int b = blockIdx.z;
  const int m0 = blockIdx.y * 64, n0 = blockIdx.x * 64;
  const float* xb = x + (size_t)b * C * N;
  const int tid = threadIdx.x;
  const int tr = tid >> 4, tc = tid & 15;
  float acc[4][4] = {};
  for (int k0 = 0; k0 < C; k0 += 16) {
    for (int i = tid; i < 64 * 16; i += 256) {
      int m = i >> 4, kk = i & 15;
      int gm = m0 + m;
      As[m][kk] = (gm < OC) ? w[(size_t)gm * C + k0 + kk] : 0.f;
    }
    for (int i = tid; i < 16 * 64; i += 256) {
      int kk = i >> 6, n = i & 63;
      int gn = n0 + n;
      Bs[kk][n] = (gn < N) ? xb[(size_t)(k0 + kk) * N + gn] : 0.f;
    }
    __syncthreads();
#pragma unroll
    for (int kk = 0; kk < 16; ++kk) {
      float a[4], bb[4];
#pragma unroll
      for (int i = 0; i < 4; i++) a[i] = As[tr * 4 + i][kk];
#pragma unroll
      for (int j = 0; j < 4; j++) bb[j] = Bs[kk][tc * 4 + j];
#pragma unroll
      for (int i = 0; i < 4; i++)
#pragma unroll
        for (int j = 0; j < 4; j++) acc[i][j] += a[i] * bb[j];
    }
    __syncthreads();
  }
  for (int i = 0; i < 4; i++) {
    int gm = m0 + tr * 4 + i;
    if (gm >= OC) continue;
    float bv = bias[gm];
    for (int j = 0; j < 4; j++) {
      int gn = n0 + tc * 4 + j;
      if (gn < N) out[((size_t)b * OC + gm) * N + gn] = acc[i][j] + bv;
    }
  }
}

// ---------------------------------------------------------------------------
// energy[b,n,m] = sum_q q[b,q,n] * k[b,q,m]
// ---------------------------------------------------------------------------
__global__ __launch_bounds__(256) void energy_kernel(
    const float* __restrict__ qg, const float* __restrict__ kg,
    float* __restrict__ e, int QKd, int N) {
  __shared__ float As[16][64];
  __shared__ float Bs[16][64];
  const int b = blockIdx.z;
  const int n0 = blockIdx.y * 64, m0 = blockIdx.x * 64;
  const float* qb = qg + (size_t)b * QKd * N;
  const float* kb = kg + (size_t)b * QKd * N;
  const int tid = threadIdx.x, tr = tid >> 4, tc = tid & 15;
  float acc[4][4] = {};
  for (int k0 = 0; k0 < QKd; k0 += 16) {
    for (int i = tid; i < 16 * 64; i += 256) {
      int kk = i >> 6, n = i & 63;
      int gn = n0 + n;
      As[kk][n] = (gn < N) ? qb[(size_t)(k0 + kk) * N + gn] : 0.f;
    }
    for (int i = tid; i < 16 * 64; i += 256) {
      int kk = i >> 6, m = i & 63;
      int gm = m0 + m;
      Bs[kk][m] = (gm < N) ? kb[(size_t)(k0 + kk) * N + gm] : 0.f;
    }
    __syncthreads();
#pragma unroll
    for (int kk = 0; kk < 16; ++kk) {
      float a[4], bb[4];
#pragma unroll
      for (int i = 0; i < 4; i++) a[i] = As[kk][tr * 4 + i];
#pragma unroll
      for (int j = 0; j < 4; j++) bb[j] = Bs[kk][tc * 4 + j];
#pragma unroll
      for (int i = 0; i < 4; i++)
#pragma unroll
        for (int j = 0; j < 4; j++) acc[i][j] += a[i] * bb[j];
    }
    __syncthreads();
  }
  for (int i = 0; i < 4; i++) {
    int gn = n0 + tr * 4 + i;
    if (gn >= N) continue;
    for (int j = 0; j < 4; j++) {
      int gm = m0 + tc * 4 + j;
      if (gm < N) e[((size_t)b * N + gn) * N + gm] = acc[i][j];
    }
  }
}

// ---------------------------------------------------------------------------
// in-place row softmax of sign*r over last dim
// ---------------------------------------------------------------------------
__global__ __launch_bounds__(256) void softmax_rows_kernel(
    float* __restrict__ e, int N, float sign) {
  const size_t row = blockIdx.x;
  float* r = e + row * (size_t)N;
  const int tid = threadIdx.x;
  __shared__ float red[4];
  float mx = -1e30f;
  for (int i = tid; i < N; i += 256) mx = fmaxf(mx, sign * r[i]);
#pragma unroll
  for (int off = 32; off; off >>= 1) mx = fmaxf(mx, __shfl_xor(mx, off, 64));
  if ((tid & 63) == 0) red[tid >> 6] = mx;
  __syncthreads();
  if (tid == 0) {
    float m2 = red[0];
    for (int i = 1; i < 4; i++) m2 = fmaxf(m2, red[i]);
    red[0] = m2;
  }
  __syncthreads();
  mx = red[0];
  __syncthreads();
  float s = 0.f;
  for (int i = tid; i < N; i += 256) {
    float v = __expf(sign * r[i] - mx);
    r[i] = v;
    s += v;
  }
#pragma unroll
  for (int off = 32; off; off >>= 1) s += __shfl_xor(s, off, 64);
  if ((tid & 63) == 0) red[tid >> 6] = s;
  __syncthreads();
  if (tid == 0) {
    float t = 0.f;
    for (int i = 0; i < 4; i++) t += red[i];
    red[0] = t;
  }
  __syncthreads();
  const float inv = 1.f / red[0];
  for (int i = tid; i < N; i += 256) r[i] *= inv;
}

// ---------------------------------------------------------------------------
// xsum[b,c,n] = x[b,c,n] + g * sum_m v[b,c,m] * A[b,n,m]
// ---------------------------------------------------------------------------
__global__ __launch_bounds__(256) void pv_add_kernel(
    const float* __restrict__ v, const float* __restrict__ A,
    const float* __restrict__ x, const float* __restrict__ gp,
    float* __restrict__ xsum, int C, int N) {
  __shared__ float Vs[64][17];
  __shared__ float At[64][17];
  const int b = blockIdx.z;
  const int c0 = blockIdx.y * 64, n0 = blockIdx.x * 64;
  const float* vb = v + (size_t)b * C * N;
  const float* Ab = A + (size_t)b * N * N;
  const int tid = threadIdx.x, tr = tid >> 4, tc = tid & 15;
  float acc[4][4] = {};
  for (int k0 = 0; k0 < N; k0 += 16) {
    for (int i = tid; i < 64 * 16; i += 256) {
      int rr = i >> 4, kk = i & 15;
      int gk = k0 + kk;
      Vs[rr][kk] = (gk < N) ? vb[(size_t)(c0 + rr) * N + gk] : 0.f;
    }
    for (int i = tid; i < 64 * 16; i += 256) {
      int rr = i >> 4, kk = i & 15;
      int gn = n0 + rr, gk = k0 + kk;
      At[rr][kk] = (gn < N && gk < N) ? Ab[(size_t)gn * N + gk] : 0.f;
    }
    __syncthreads();
#pragma unroll
    for (int kk = 0; kk < 16; ++kk) {
      float a[4], bb[4];
#pragma unroll
      for (int i = 0; i < 4; i++) a[i] = Vs[tr * 4 + i][kk];
#pragma unroll
      for (int j = 0; j < 4; j++) bb[j] = At[tc * 4 + j][kk];
#pragma unroll
      for (int i = 0; i < 4; i++)
#pragma unroll
        for (int j = 0; j < 4; j++) acc[i][j] += a[i] * bb[j];
    }
    __syncthreads();
  }
  const float g = *gp;
  for (int i = 0; i < 4; i++) {
    int gc = c0 + tr * 4 + i;
    for (int j = 0; j < 4; j++) {
      int gn = n0 + tc * 4 + j;
      if (gn < N) {
        size_t idx = ((size_t)b * C + gc) * N + gn;
        xsum[idx] = x[idx] + g * acc[i][j];
      }
    }
  }
}

// ---------------------------------------------------------------------------
// gram with split-K: e[b,c,d] += sum_{k in range} x[b,c,k] * x[b,d,k]
// requires e pre-zeroed. grid (C/64, C/64, B*KS)
// ---------------------------------------------------------------------------
template <int KS>
__global__ __launch_bounds__(256) void gram_split_kernel(
    const float* __restrict__ x, float* __restrict__ e, int C, int N) {
  __shared__ float Xs[64][17];
  __shared__ float Ys[64][17];
  const int b = blockIdx.z / KS;
  const int ks = blockIdx.z % KS;
  const int kper = ((N + KS * 16 - 1) / (KS * 16)) * 16;
  const int kstart = ks * kper;
  const int kend = min(N, kstart + kper);
  const int c0 = blockIdx.y * 64, d0 = blockIdx.x * 64;
  const float* xb = x + (size_t)b * C * N;
  const int tid = threadIdx.x, tr = tid >> 4, tc = tid & 15;
  float acc[4][4] = {};
  for (int k0 = kstart; k0 < kend; k0 += 16) {
    for (int i = tid; i < 1024; i += 256) {
      int rr = i >> 4, kk = i & 15;
      int gk = k0 + kk;
      Xs[rr][kk] = (gk < N) ? xb[(size_t)(c0 + rr) * N + gk] : 0.f;
    }
    for (int i = tid; i < 1024; i += 256) {
      int rr = i >> 4, kk = i & 15;
      int gk = k0 + kk;
      Ys[rr][kk] = (gk < N) ? xb[(size_t)(d0 + rr) * N + gk] : 0.f;
    }
    __syncthreads();
#pragma unroll
    for (int kk = 0; kk < 16; ++kk) {
      float a[4], bb[4];
#pragma unroll
      for (int i = 0; i < 4; i++) a[i] = Xs[tr * 4 + i][kk];
#pragma unroll
      for (int j = 0; j < 4; j++) bb[j] = Ys[tc * 4 + j][kk];
#pragma unroll
      for (int i = 0; i < 4; i++)
#pragma unroll
        for (int j = 0; j < 4; j++) acc[i][j] += a[i] * bb[j];
    }
    __syncthreads();
  }
  for (int i = 0; i < 4; i++)
    for (int j = 0; j < 4; j++)
      atomicAdd(&e[((size_t)b * C + c0 + tr * 4 + i) * C + d0 + tc * 4 + j],
                acc[i][j]);
}

// ---------------------------------------------------------------------------
// xsum[b,c,n] += sum_d (w1*Aown[b,c,d] + w2*Aoth[b,c,d]) * x[b,d,n]
// ---------------------------------------------------------------------------
__global__ __launch_bounds__(256) void chan_use_kernel(
    const float* __restrict__ Aown, const float* __restrict__ Aoth,
    const float* __restrict__ w1p, const float* __restrict__ w2p,
    const float* __restrict__ x, float* __restrict__ xsum, int C, int N) {
  __shared__ float Ms[64][17];
  __shared__ float Bs[16][64];
  const int b = blockIdx.z;
  const int c0 = blockIdx.y * 64, n0 = blockIdx.x * 64;
  const float w1 = *w1p, w2 = *w2p;
  const float* Ao = Aown + (size_t)b * C * C;
  const float* Ax = Aoth + (size_t)b * C * C;
  const float* xb = x + (size_t)b * C * N;
  const int tid = threadIdx.x, tr = tid >> 4, tc = tid & 15;
  float acc[4][4] = {};
  for (int k0 = 0; k0 < C; k0 += 16) {
    for (int i = tid; i < 1024; i += 256) {
      int rr = i >> 4, kk = i & 15;
      size_t ii = (size_t)(c0 + rr) * C + k0 + kk;
      Ms[rr][kk] = w1 * Ao[ii] + w2 * Ax[ii];
    }
    for (int i = tid; i < 1024; i += 256) {
      int kk = i >> 6, n = i & 63;
      int gn = n0 + n;
      Bs[kk][n] = (gn < N) ? xb[(size_t)(k0 + kk) * N + gn] : 0.f;
    }
    __syncthreads();
#pragma unroll
    for (int kk = 0; kk < 16; ++kk) {
      float a[4], bb[4];
#pragma unroll
      for (int i = 0; i < 4; i++) a[i] = Ms[tr * 4 + i][kk];
#pragma unroll
      for (int j = 0; j < 4; j++) bb[j] = Bs[kk][tc * 4 + j];
#pragma unroll
      for (int i = 0; i < 4; i++)
#pragma unroll
        for (int j = 0; j < 4; j++) acc[i][j] += a[i] * bb[j];
    }
    __syncthreads();
  }
  for (int i = 0; i < 4; i++) {
    int gc = c0 + tr * 4 + i;
    for (int j = 0; j < 4; j++) {
      int gn = n0 + tc * 4 + j;
      if (gn < N) xsum[((size_t)b * C + gc) * N + gn] += acc[i][j];
    }
  }
}

// ---------------------------------------------------------------------------
// bias fill: buf[b][o][p] = bias[o]
// ---------------------------------------------------------------------------
__global__ __launch_bounds__(256) void bias_fill_kernel(
    float* __restrict__ buf, const float* __restrict__ bias, int OC, int N,
    int total) {
  const int i = blockIdx.x * 256 + threadIdx.x;
  if (i >= total) return;
  buf[i] = bias[(i / N) % OC];
}

// ---------------------------------------------------------------------------
// offset conv as tiled GEMM: om[b,o,p] += sum_{K=c*9+tap} w[o,K]*patch(K,p)
// split-K with atomicAdd (om pre-filled with bias). M=27(pad 32), N-tile 64.
// grid (ceil(N/64), B*KS)
// ---------------------------------------------------------------------------
template <int KS>
__global__ __launch_bounds__(256) void offconv_gemm_kernel(
    const float* __restrict__ xsum, const float* __restrict__ ow,
    float* __restrict__ om, int H, int Wd) {
  constexpr int C = 256, KTOT = C * 9;
  constexpr int KPER = KTOT / KS;
  __shared__ float As[16][33];  // [kk][o]
  __shared__ float Bs[16][64];  // [kk][n]
  const int N = H * Wd;
  const int p0 = blockIdx.x * 64;
  const int b = blockIdx.y / KS;
  const int ks = blockIdx.y % KS;
  const int tid = threadIdx.x;
  const int to = tid & 31, tp = tid >> 5;  // o index, p-group (8 p each)
  const float* xb = xsum + (size_t)b * C * N;
  float acc[8] = {};
  const int kstart = ks * KPER;
  for (int k0 = kstart; k0 < kstart + KPER; k0 += 16) {
    for (int i = tid; i < 512; i += 256) {
      int kk = i >> 5, o = i & 31;
      As[kk][o] = (o < 27) ? ow[(size_t)o * KTOT + k0 + kk] : 0.f;
    }
    for (int i = tid; i < 1024; i += 256) {
      int kk = i >> 6, n = i & 63;
      int K = k0 + kk;
      int c = K / 9, tap = K - c * 9;
      int dy = tap / 3 - 1, dx = tap - (tap / 3) * 3 - 1;
      int p = p0 + n;
      float v = 0.f;
      if (p < N) {
        int h = p / Wd, w = p - (p / Wd) * Wd;
        int hh = h + dy, ww = w + dx;
        if (hh >= 0 && hh < H && ww >= 0 && ww < Wd)
          v = xb[(size_t)c * N + hh * Wd + ww];
      }
      Bs[kk][n] = v;
    }
    __syncthreads();
#pragma unroll
    for (int kk = 0; kk < 16; ++kk) {
      float a = As[kk][to];
#pragma unroll
      for (int j = 0; j < 8; j++) acc[j] += a * Bs[kk][tp * 8 + j];
    }
    __syncthreads();
  }
  if (to < 27) {
    for (int j = 0; j < 8; j++) {
      int p = p0 + tp * 8 + j;
      if (p < N) atomicAdd(&om[((size_t)b * 27 + to) * N + p], acc[j]);
    }
  }
}

// ---------------------------------------------------------------------------
// transpose DCN weights (O,C,3,3) -> Wt[K=k*256+c][o]
// ---------------------------------------------------------------------------
__global__ __launch_bounds__(256) void transposeW_kernel(
    const float* __restrict__ W, float* __restrict__ Wt, int C) {
  const int i = blockIdx.x * 256 + threadIdx.x;
  if (i >= C * C * 9) return;
  const int k = i % 9;
  const int c = (i / 9) % C;
  const int o = i / (9 * C);
  Wt[((size_t)k * C + c) * C + o] = W[i];
}

// ---------------------------------------------------------------------------
// precompute bilinear gather indices & weights per (b, kpos, p)
// wgt includes sigmoid(mask) and validity.
// ---------------------------------------------------------------------------
__global__ __launch_bounds__(256) void prep_offsets_kernel(
    const float* __restrict__ om, int4* __restrict__ idx4,
    float4* __restrict__ wgt4, int B, int H, int Wd) {
  const int N = H * Wd;
  const int i = blockIdx.x * 256 + threadIdx.x;
  if (i >= B * 9 * N) return;
  const int p = i % N;
  const int k = (i / N) % 9;
  const int b = i / (9 * N);
  const float* omb = om + (size_t)b * 27 * N;
  const float offy = omb[(size_t)k * N + p];
  const float offx = omb[(size_t)(9 + k) * N + p];
  const float mraw = omb[(size_t)(18 + k) * N + p];
  const float mval = 1.f / (1.f + __expf(-mraw));
  const int ky = k / 3, kx = k - (k / 3) * 3;
  const int h = p / Wd, w = p - (p / Wd) * Wd;
  const float py = offy + (float)(h + ky - 1);
  const float px = offx + (float)(w + kx - 1);
  const float y0f = floorf(py), x0f = floorf(px);
  const float wy = py - y0f, wx = px - x0f;
  const int y0 = (int)y0f, x0 = (int)x0f;
  int idxs[4];
  float wts[4];
  const int ys[2] = {y0, y0 + 1};
  const int xs2[2] = {x0, x0 + 1};
  const float wyv[2] = {1.f - wy, wy};
  const float wxv[2] = {1.f - wx, wx};
#pragma unroll
  for (int a = 0; a < 2; a++)
#pragma unroll
    for (int bb = 0; bb < 2; bb++) {
      const int yi = ys[a], xi = xs2[bb];
      const bool valid = (yi >= 0) && (yi < H) && (xi >= 0) && (xi < Wd);
      const int yc = min(max(yi, 0), H - 1);
      const int xc = min(max(xi, 0), Wd - 1);
      idxs[a * 2 + bb] = yc * Wd + xc;
      wts[a * 2 + bb] = valid ? wyv[a] * wxv[bb] * mval : 0.f;
    }
  idx4[i] = make_int4(idxs[0], idxs[1], idxs[2], idxs[3]);
  wgt4[i] = make_float4(wts[0], wts[1], wts[2], wts[3]);
}

// ---------------------------------------------------------------------------
// DCN implicit GEMM: out[b,o,p] (+)= sum_K Wt[K][o] * gathered(K,p)
// K = kpos*256 + c. 128x64 tile, thread = 8o x 4p.
// KSPLIT==1: direct store with bias. KSPLIT>1: atomicAdd (out pre-biased).
// grid (ceil(N/64), 2, B*KSPLIT)
// ---------------------------------------------------------------------------
template <int KSPLIT>
__global__ __launch_bounds__(256) void dcn_gemm_kernel(
    const float* __restrict__ xsum, const int4* __restrict__ idx4,
    const float4* __restrict__ wgt4, const float* __restrict__ Wt,
    const float* __restrict__ bias, float* __restrict__ out, int N) {
  constexpr int C = 256, KTOT = 2304, KPER = KTOT / KSPLIT;
  __shared__ float As[16][128];  // [kk][m]
  __shared__ float Bs[16][64];   // [kk][n]
  __shared__ int si0[64], si1[64], si2[64], si3[64];
  __shared__ float sw0[64], sw1[64], sw2[64], sw3[64];
  const int n0 = blockIdx.x * 64;
  const int m0 = blockIdx.y * 128;
  const int b = blockIdx.z / KSPLIT;
  const int ks = blockIdx.z % KSPLIT;
  const int tid = threadIdx.x, tr = tid >> 4, tc = tid & 15;
  const float* xb = xsum + (size_t)b * C * N;
  float acc[8][4] = {};
  const int kstart = ks * KPER;
  for (int k0 = kstart; k0 < kstart + KPER; k0 += 16) {
    const int kpos = k0 >> 8, c0 = k0 & 255;
    if (k0 == kstart || c0 == 0) {
      if (tid < 64) {
        const int p = n0 + tid;
        if (p < N) {
          const size_t base = ((size_t)b * 9 + kpos) * N + p;
          const int4 iv = idx4[base];
          const float4 wv = wgt4[base];
          si0[tid] = iv.x; si1[tid] = iv.y; si2[tid] = iv.z; si3[tid] = iv.w;
          sw0[tid] = wv.x; sw1[tid] = wv.y; sw2[tid] = wv.z; sw3[tid] = wv.w;
        } else {
          si0[tid] = si1[tid] = si2[tid] = si3[tid] = 0;
          sw0[tid] = sw1[tid] = sw2[tid] = sw3[tid] = 0.f;
        }
      }
      __syncthreads();
    }
#pragma unroll
    for (int i = 0; i < 8; i++) {
      const int idx = tid + i * 256;
      const int kk = idx >> 7, m = idx & 127;
      As[kk][m] = Wt[(size_t)(k0 + kk) * C + m0 + m];
    }
#pragma unroll
    for (int i = 0; i < 4; i++) {
      const int idx = tid + i * 256;
      const int kk = idx >> 6, n = idx & 63;
      const float* row = xb + (size_t)(c0 + kk) * N;
      Bs[kk][n] = sw0[n] * row[si0[n]] + sw1[n] * row[si1[n]] +
                  sw2[n] * row[si2[n]] + sw3[n] * row[si3[n]];
    }
    __syncthreads();
#pragma unroll
    for (int kk = 0; kk < 16; ++kk) {
      float a[8], bb[4];
#pragma unroll
      for (int i = 0; i < 8; i++) a[i] = As[kk][tr * 8 + i];
#pragma unroll
      for (int j = 0; j < 4; j++) bb[j] = Bs[kk][tc * 4 + j];
#pragma unroll
      for (int i = 0; i < 8; i++)
#pragma unroll
        for (int j = 0; j < 4; j++) acc[i][j] += a[i] * bb[j];
    }
    __syncthreads();
  }
#pragma unroll
  for (int i = 0; i < 8; i++) {
    const int m = m0 + tr * 8 + i;
#pragma unroll
    for (int j = 0; j < 4; j++) {
      const int n = n0 + tc * 4 + j;
      if (n < N) {
        const size_t o = ((size_t)b * C + m) * N + n;
        if (KSPLIT == 1)
          out[o] = acc[i][j] + bias[m];
        else
          atomicAdd(&out[o], acc[i][j]);
      }
    }
  }
}

// ---------------------------------------------------------------------------
extern "C" void kernel_launch(void* const* d_in, const int* in_sizes, int n_in,
                              void* d_out, int out_size, void* d_ws, size_t ws_size,
                              hipStream_t stream) {
  const float* t_in = (const float*)d_in[0];
  const float* s_in = (const float*)d_in[1];
  const float* t_qw = (const float*)d_in[2];
  const float* t_qb = (const float*)d_in[3];
  const float* t_kw = (const float*)d_in[4];
  const float* t_kb = (const float*)d_in[5];
  const float* t_vw = (const float*)d_in[6];
  const float* t_vb = (const float*)d_in[7];
  const float* t_g = (const float*)d_in[8];
  const float* s_qw = (const float*)d_in[9];
  const float* s_qb = (const float*)d_in[10];
  const float* s_kw = (const float*)d_in[11];
  const float* s_kb = (const float*)d_in[12];
  const float* s_vw = (const float*)d_in[13];
  const float* s_vb = (const float*)d_in[14];
  const float* s_g = (const float*)d_in[15];
  const float* w_t_ch = (const float*)d_in[16];
  const float* w_s_ch = (const float*)d_in[17];
  const float* w_s2t = (const float*)d_in[18];
  const float* w_t2s = (const float*)d_in[19];
  const float* t_off_w = (const float*)d_in[20];
  const float* t_off_b = (const float*)d_in[21];
  const float* t_dcn_w = (const float*)d_in[22];
  const float* t_dcn_b = (const float*)d_in[23];
  const float* s_off_w = (const float*)d_in[24];
  const float* s_off_b = (const float*)d_in[25];
  const float* s_dcn_w = (const float*)d_in[26];
  const float* s_dcn_b = (const float*)d_in[27];
  (void)in_sizes; (void)n_in; (void)out_size; (void)ws_size;

  constexpr int Bn = 16, C = 256, QKd = 32;
  constexpr int HT = 15, WT = 15, NT = HT * WT;    // 225
  constexpr int HS = 31, WS2 = 31, NS = HS * WS2;  // 961

  float* ws = (float*)d_ws;
  size_t off = 0;
  auto alloc = [&](size_t n) { float* p = ws + off; off += n; return p; };
  float* q_t = alloc((size_t)Bn * QKd * NT);
  float* k_t = alloc((size_t)Bn * QKd * NT);
  float* v_t = alloc((size_t)Bn * C * NT);
  float* q_s = alloc((size_t)Bn * QKd * NS);
  float* k_s = alloc((size_t)Bn * QKd * NS);
  float* v_s = alloc((size_t)Bn * C * NS);
  float* At = alloc((size_t)Bn * NT * NT);
  float* As = alloc((size_t)Bn * NS * NS);
  float* xt = alloc((size_t)Bn * C * NT);
  float* xs = alloc((size_t)Bn * C * NS);
  float* Atc = alloc((size_t)Bn * C * C);
  float* Asc = alloc((size_t)Bn * C * C);
  float* om_t = alloc((size_t)Bn * 27 * NT);
  float* om_s = alloc((size_t)Bn * 27 * NS);
  float* Wt_t = alloc((size_t)9 * C * C);
  float* Wt_s = alloc((size_t)9 * C * C);
  // gather tables (int4/float4, 4 floats each)
  float* prep_t = alloc((size_t)Bn * 9 * NT * 8);
  float* prep_s = alloc((size_t)Bn * 9 * NS * 8);
  int4* idx_t = (int4*)prep_t;
  float4* wgt_t = (float4*)(prep_t + (size_t)Bn * 9 * NT * 4);
  int4* idx_s = (int4*)prep_s;
  float4* wgt_s = (float4*)(prep_s + (size_t)Bn * 9 * NS * 4);

  dim3 blk(256);

  // q, k, v (conv1x1)
  conv1x1_kernel<<<dim3(4, 1, Bn), blk, 0, stream>>>(t_in, t_qw, t_qb, q_t, C, NT, QKd);
  conv1x1_kernel<<<dim3(4, 1, Bn), blk, 0, stream>>>(t_in, t_kw, t_kb, k_t, C, NT, QKd);
  conv1x1_kernel<<<dim3(4, 4, Bn), blk, 0, stream>>>(t_in, t_vw, t_vb, v_t, C, NT, C);
  conv1x1_kernel<<<dim3(16, 1, Bn), blk, 0, stream>>>(s_in, s_qw, s_qb, q_s, C, NS, QKd);
  conv1x1_kernel<<<dim3(16, 1, Bn), blk, 0, stream>>>(s_in, s_kw, s_kb, k_s, C, NS, QKd);
  conv1x1_kernel<<<dim3(16, 4, Bn), blk, 0, stream>>>(s_in, s_vw, s_vb, v_s, C, NS, C);

  // spatial attention
  energy_kernel<<<dim3(4, 4, Bn), blk, 0, stream>>>(q_t, k_t, At, QKd, NT);
  energy_kernel<<<dim3(16, 16, Bn), blk, 0, stream>>>(q_s, k_s, As, QKd, NS);
  softmax_rows_kernel<<<dim3(Bn * NT), blk, 0, stream>>>(At, NT, 1.f);
  softmax_rows_kernel<<<dim3(Bn * NS), blk, 0, stream>>>(As, NS, 1.f);
  pv_add_kernel<<<dim3(4, 4, Bn), blk, 0, stream>>>(v_t, At, t_in, t_g, xt, C, NT);
  pv_add_kernel<<<dim3(16, 4, Bn), blk, 0, stream>>>(v_s, As, s_in, s_g, xs, C, NS);

  // channel attention (A = softmax(-gram)), split-K gram
  hipMemsetAsync(Atc, 0, (size_t)Bn * C * C * sizeof(float), stream);
  hipMemsetAsync(Asc, 0, (size_t)Bn * C * C * sizeof(float), stream);
  gram_split_kernel<2><<<dim3(4, 4, Bn * 2), blk, 0, stream>>>(t_in, Atc, C, NT);
  gram_split_kernel<4><<<dim3(4, 4, Bn * 4), blk, 0, stream>>>(s_in, Asc, C, NS);
  softmax_rows_kernel<<<dim3(Bn * C), blk, 0, stream>>>(Atc, C, -1.f);
  softmax_rows_kernel<<<dim3(Bn * C), blk, 0, stream>>>(Asc, C, -1.f);
  chan_use_kernel<<<dim3(4, 4, Bn), blk, 0, stream>>>(Atc, Asc, w_t_ch, w_s2t, t_in, xt, C, NT);
  chan_use_kernel<<<dim3(16, 4, Bn), blk, 0, stream>>>(Asc, Atc, w_s_ch, w_t2s, s_in, xs, C, NS);

  // offsets: om pre-filled with bias, split-K GEMM accumulates
  bias_fill_kernel<<<dim3((Bn * 27 * NT + 255) / 256), blk, 0, stream>>>(om_t, t_off_b, 27, NT, Bn * 27 * NT);
  bias_fill_kernel<<<dim3((Bn * 27 * NS + 255) / 256), blk, 0, stream>>>(om_s, s_off_b, 27, NS, Bn * 27 * NS);
  offconv_gemm_kernel<8><<<dim3(4, Bn * 8), blk, 0, stream>>>(xt, t_off_w, om_t, HT, WT);
  offconv_gemm_kernel<2><<<dim3(16, Bn * 2), blk, 0, stream>>>(xs, s_off_w, om_s, HS, WS2);

  // DCN prep
  transposeW_kernel<<<dim3((C * C * 9 + 255) / 256), blk, 0, stream>>>(t_dcn_w, Wt_t, C);
  transposeW_kernel<<<dim3((C * C * 9 + 255) / 256), blk, 0, stream>>>(s_dcn_w, Wt_s, C);
  prep_offsets_kernel<<<dim3((Bn * 9 * NT + 255) / 256), blk, 0, stream>>>(om_t, idx_t, wgt_t, Bn, HT, WT);
  prep_offsets_kernel<<<dim3((Bn * 9 * NS + 255) / 256), blk, 0, stream>>>(om_s, idx_s, wgt_s, Bn, HS, WS2);

  float* out_t = (float*)d_out;
  float* out_s = out_t + (size_t)Bn * C * NT;
  // t-side: split-K=4 with bias prefill; s-side: direct store
  bias_fill_kernel<<<dim3((Bn * C * NT + 255) / 256), blk, 0, stream>>>(out_t, t_dcn_b, C, NT, Bn * C * NT);
  dcn_gemm_kernel<4><<<dim3(4, 2, Bn * 4), blk, 0, stream>>>(xt, idx_t, wgt_t, Wt_t, t_dcn_b, out_t, NT);
  dcn_gemm_kernel<1><<<dim3(16, 2, Bn), blk, 0, stream>>>(xs, idx_s, wgt_s, Wt_s, s_dcn_b, out_s, NS);
}